// Round 16
// baseline (189.069 us; speedup 1.0000x reference)
//
#include <hip/hip_runtime.h>

// TemporalLogicLayer R16: exact revert to R13 (verified 188 us, absmax 0.0039).
// out[b,t,o] = max_{s>=t} sigmoid(5*(relu(relu([cummax(P[t..s])|P[s]]W1+b1)W2+b2)W3+b3))
//
// R14/R15 post-mortem: hoisting item-invariant MFMA A-operand fragments into
// registers (56 or 40 VGPR) fails correctness DETERMINISTICALLY (absmax
// 0.9355 in both, bit-identical) with zero source-level logic diff vs R13.
// Not register pressure (R15 was ~110 < 128 cap; R10 proved spills are
// correct-but-slow here). Conclusion: long-lived MFMA operand vectors across
// this barrier-dense item loop miscompile -> weight fragments MUST be
// reloaded in-loop (L2-resident, cheap). Hoisting is off the table.
//
// Structure (verified): balanced 9-tile-units/wave GEMM split (wave w owns
// f-tile w x 8 row-tiles + row-tile w of the shared 9th tile); cmx/h LDS
// overlay (38944 B -> 4 blocks/CU); register carry of running cummax;
// z-domain register max with flush-to-slots on t-change; PW precomputes the
// t-invariant half of L1; 1024-block grid, contiguous t-major item ranges;
// 3 dispatches (prep / main / finalize).

#define TT 128
#define BB 32
#define DD 128
#define OO 64
#define NP 144
#define HSTR2 152
#define KSLOT 17
#define NBLK 1024
#define ZOFF (128*HSTR2)                            // zero strip, f16 offset 19456

typedef __attribute__((ext_vector_type(8))) _Float16 half8;
typedef __attribute__((ext_vector_type(4))) _Float16 half4;
typedef __attribute__((ext_vector_type(4))) float f32x4;

// ws layout (bytes)
#define W1T_OFF 0                                   // f16 [144][128] (K<128 half)
#define W2T_OFF (W1T_OFF + 144*128*2)               // f16 [144][160]
#define W3T_OFF (W2T_OFF + 144*160*2)               // f16 [64][160]
#define B1P_OFF (W3T_OFF + 64*160*2)                // f32 [144]
#define B2P_OFF (B1P_OFF + 144*4)                   // f32 [144]
#define PW_OFF  (B2P_OFF + 144*4)                   // f16 [4096][144]
#define PF_OFF  (PW_OFF + 4096*144*2)               // f16 [32][128][128]
#define SLOT_OFF (PF_OFF + 32*128*128*2)            // f16 [128][KSLOT][32][64]

#define MFMA(A, B, C) __builtin_amdgcn_mfma_f32_16x16x32_f16((A), (B), (C), 0, 0, 0)

__device__ __forceinline__ half8 h8max(half8 a, half8 b) {
    half8 r;
    #pragma unroll
    for (int i = 0; i < 8; ++i) r[i] = (a[i] > b[i]) ? a[i] : b[i];
    return r;
}

// largest bid with range_start(bid) = (bid*33)>>4 <= it   (1024-block partition)
__device__ __forceinline__ int bid_of(int it) {
    int bb = (16 * it) / 33;
    while ((((bb + 1) * 33) >> 4) <= it) ++bb;
    while (((bb * 33) >> 4) > it) --bb;
    return bb;
}

// ---------- prep (240 blocks x 256) ----------
__global__ void tll_prep(const float* __restrict__ P,
                         const float* __restrict__ W1, const float* __restrict__ b1,
                         const float* __restrict__ W2, const float* __restrict__ b2,
                         const float* __restrict__ W3, char* __restrict__ ws) {
    __shared__ _Float16 w1s[144 * 130];             // 37440 B (PW blocks only)
    const int blk = blockIdx.x, tid = threadIdx.x;
    if (blk < 144) {
        _Float16* W1t = (_Float16*)(ws + W1T_OFF);
        _Float16* W2t = (_Float16*)(ws + W2T_OFF);
        _Float16* W3t = (_Float16*)(ws + W3T_OFF);
        float*    b1p = (float*)(ws + B1P_OFF);
        float*    b2p = (float*)(ws + B2P_OFF);
        int idx = blk * 256 + tid;
        if (idx < 144*128) {                        // W1t[n][k] = W1[k][n], k<128
            int n = idx >> 7, k = idx & 127;
            W1t[idx] = (_Float16)((n < 132) ? W1[k*132 + n] : 0.f);
        }
        if (idx < 144*160) {                        // W2t[n][k] = W2[k][n]
            int n = idx / 160, k = idx - n*160;
            W2t[idx] = (_Float16)((n < 132 && k < 132) ? W2[k*132 + n] : 0.f);
        }
        if (idx < 64*160) {                         // W3t[o][k] = W3[k][o]
            int o = idx / 160, k = idx - o*160;
            W3t[idx] = (_Float16)((k < 132) ? W3[k*64 + o] : 0.f);
        }
        if (idx < 144) {
            b1p[idx] = (idx < 132) ? b1[idx] : 0.f;
            b2p[idx] = (idx < 132) ? b2[idx] : 0.f;
        }
    } else if (blk < 208) {
        // PW[row][n] = P[row] @ W1[128:256, :], row = s*32+b (coalesced+LDS)
        _Float16* PW = (_Float16*)(ws + PW_OFF);
        const int blkp = blk - 144;
        for (int i = tid; i < 128*132; i += 256) {  // i: k-major, n consecutive
            int k = i / 132, n = i - k*132;
            w1s[n*130 + k] = (_Float16)W1[(128 + k)*132 + n];
        }
        for (int i = tid; i < 12*130; i += 256) {   // zero pad n = 132..143
            int n = 132 + i/130, k = i - (i/130)*130;
            w1s[n*130 + k] = (_Float16)0.f;
        }
        __syncthreads();
        const int w = tid >> 6, lane = tid & 63;
        const int ln = lane & 15, q = lane >> 4;
        const int row = (blkp*4 + w)*16 + ln;       // 0..4095
        const int b_ = row & 31, s_ = row >> 5;
        const float* pp = P + b_*(TT*DD) + s_*DD;
        half8 Bf[4];
        #pragma unroll
        for (int kst = 0; kst < 4; ++kst) {
            f32x4 p0 = *(const f32x4*)(pp + kst*32 + q*8);
            f32x4 p1 = *(const f32x4*)(pp + kst*32 + q*8 + 4);
            half8 h;
            #pragma unroll
            for (int i = 0; i < 4; ++i) { h[i] = (_Float16)p0[i]; h[4+i] = (_Float16)p1[i]; }
            Bf[kst] = h;
        }
        for (int mt = 0; mt < 9; ++mt) {
            f32x4 acc = (f32x4){0.f, 0.f, 0.f, 0.f};
            #pragma unroll
            for (int kst = 0; kst < 4; ++kst) {
                half8 A = *(const half8*)&w1s[(mt*16 + ln)*130 + kst*32 + q*8];
                acc = MFMA(A, Bf[kst], acc);
            }
            half4 hv;
            #pragma unroll
            for (int i = 0; i < 4; ++i) hv[i] = (_Float16)acc[i];
            *(half4*)(PW + (size_t)row*NP + mt*16 + q*4) = hv;
        }
    } else {
        // Pf[b] = f16(P[b])
        _Float16* Pf = (_Float16*)(ws + PF_OFF);
        const int b = blk - 208;
        const f32x4* src = (const f32x4*)(P + (size_t)b * TT * DD);
        half4* dst = (half4*)(Pf + (size_t)b * TT * DD);
        for (int i = tid; i < TT*DD/4; i += 256) {
            f32x4 v = src[i];
            half4 h;
            #pragma unroll
            for (int j = 0; j < 4; ++j) h[j] = (_Float16)v[j];
            dst[i] = h;
        }
    }
}

// ---------- finalize (128 blocks x 512): out = sigmoid(5 * max_k slots) ----------
__global__ void tll_finalize(const char* __restrict__ ws, float* __restrict__ out) {
    const int t = blockIdx.x, tid = threadIdx.x;
    const int g = t >> 2;
    const int it_s = 2*g*(65 - g) + (t - 4*g)*(32 - g);
    const int it_e = it_s + (32 - g);
    const int n = bid_of(it_e - 1) - bid_of(it_s) + 1;     // <= KSLOT
    const _Float16* slots = (const _Float16*)(ws + SLOT_OFF) + (size_t)t * KSLOT * 2048;
    const int cell = tid * 4;                              // 2048 cells: b*64+o
    half4 h = *(const half4*)(slots + cell);
    f32x4 v;
    #pragma unroll
    for (int i = 0; i < 4; ++i) v[i] = (float)h[i];
    for (int k = 1; k < n; ++k) {
        half4 u = *(const half4*)(slots + k*2048 + cell);
        #pragma unroll
        for (int i = 0; i < 4; ++i) v[i] = fmaxf(v[i], (float)u[i]);
    }
    f32x4 y;
    #pragma unroll
    for (int i = 0; i < 4; ++i) y[i] = 1.f / (1.f + __expf(-5.f * v[i]));
    const int b = cell >> 6, o = cell & 63;
    *(f32x4*)(out + (size_t)b*(TT*OO) + t*OO + o) = y;
}

// ---------- main ----------
__global__ __launch_bounds__(512, 4) void tll_main(
    const float* __restrict__ b3, char* __restrict__ ws)
{
    extern __shared__ char smem[];
    _Float16* hB  = (_Float16*)smem;                // overlay: cmx[128][128]sw /
    _Float16* cmx = hB;                             //          h[128][152]
    const _Float16* zstrip = hB + ZOFF;             // 32 B zeros (kst=4, q>=2)

    const _Float16* W1t = (const _Float16*)(ws + W1T_OFF);
    const _Float16* W2t = (const _Float16*)(ws + W2T_OFF);
    const _Float16* W3t = (const _Float16*)(ws + W3T_OFF);
    const float*    b1p = (const float*)(ws + B1P_OFF);
    const float*    b2p = (const float*)(ws + B2P_OFF);
    const _Float16* PW  = (const _Float16*)(ws + PW_OFF);
    const _Float16* Pf  = (const _Float16*)(ws + PF_OFF);
    _Float16*       slots = (_Float16*)(ws + SLOT_OFF);

    const int tid = threadIdx.x, w = tid >> 6, lane = tid & 63;
    const int ln = lane & 15, q = lane >> 4;
    const int fw0 = w*16;                           // this wave's f-tile cols
    const int og = w >> 1, rg3 = w & 1;             // L3 + flush roles

    // zero strip (outside both cmx [0,16384) and h rows [0,19456))
    if (tid < 16) hB[ZOFF + tid] = (_Float16)0.f;

    const int sb = tid >> 4, dblk = tid & 15, d0 = dblk*8;  // staging role
    const _Float16* pfb = Pf + (size_t)sb*(TT*DD) + d0;

    const int bid = blockIdx.x;
    int it = (bid*33) >> 4;                          // contiguous t-major ranges
    const int hi = ((bid + 1)*33) >> 4;

    int cur_t = -1;
    f32x4 rz0 = (f32x4){-1e30f,-1e30f,-1e30f,-1e30f};  // z-domain max, b=ln
    f32x4 rz1 = rz0;                                    // b=16+ln
    half8 mi;                                           // carried cummax Pf[b,t..s0-1,d]
    __syncthreads();

    for (; it < hi; ++it) {
        // ---- decode item -> (t, c) ----
        int g = (int)((65.0f - sqrtf((float)(4225 - 2*it))) * 0.5f);
        if (g < 0) g = 0; if (g > 31) g = 31;
        while (g > 0 && 2*g*(65 - g) > it) --g;
        while (2*(g+1)*(65 - (g+1)) <= it) ++g;
        int rem = it - 2*g*(65 - g);
        int ntc = 32 - g;
        int t  = 4*g + rem/ntc;
        int c  = rem - (rem/ntc)*ntc;
        int s0 = t + 4*c;

        // ---- t-change: flush z-max to slot, reset + scan-init carry ----
        if (t != cur_t) {                            // block-uniform branch
            if (cur_t >= 0) {
                float* scr = (float*)hB;             // hB fully dead here
                if (rg3 == 1) {
                    *(f32x4*)(scr + (og*64 + lane)*8)     = rz0;
                    *(f32x4*)(scr + (og*64 + lane)*8 + 4) = rz1;
                }
                __syncthreads();
                if (rg3 == 0) {
                    f32x4 p0 = *(const f32x4*)(scr + (og*64 + lane)*8);
                    f32x4 p1 = *(const f32x4*)(scr + (og*64 + lane)*8 + 4);
                    #pragma unroll
                    for (int i = 0; i < 4; ++i) {
                        rz0[i] = fmaxf(rz0[i], p0[i]);
                        rz1[i] = fmaxf(rz1[i], p1[i]);
                    }
                    int k = bid - bid_of(2*(cur_t >> 2)*(65 - (cur_t >> 2))
                                         + (cur_t - 4*(cur_t >> 2))*(32 - (cur_t >> 2)));
                    _Float16* sp = slots + ((size_t)cur_t*KSLOT + k)*2048;
                    int o = og*16 + q*4;
                    half4 z0, z1;
                    #pragma unroll
                    for (int i = 0; i < 4; ++i) { z0[i] = (_Float16)rz0[i]; z1[i] = (_Float16)rz1[i]; }
                    __builtin_nontemporal_store(z0, (half4*)(sp + ln*64 + o));
                    __builtin_nontemporal_store(z1, (half4*)(sp + (16+ln)*64 + o));
                }
                __syncthreads();                     // protect scr before staging
            }
            cur_t = t;
            rz0 = (f32x4){-1e30f,-1e30f,-1e30f,-1e30f};
            rz1 = rz0;
            #pragma unroll
            for (int i = 0; i < 8; ++i) mi[i] = (_Float16)(-65504.0f);
            for (int s = t; s < s0; ++s)             // nonempty only at block start
                mi = h8max(mi, *(const half8*)(pfb + s*DD));
        }

        // ---- stage cmx: fold 4 steps onto carried mi ----
        #pragma unroll
        for (int j = 0; j < 4; ++j) {
            int s = s0 + j; if (s > 127) s = 127;    // dup of valid s=127, same b
            mi = h8max(mi, *(const half8*)(pfb + s*DD));
            int row = j*32 + sb;
            *(half8*)(cmx + row*128 + ((dblk ^ (row & 15))*8)) = mi;
        }
        __syncthreads();                             // [A]

        // ---- L1': balanced — wave w: f-tile w x 8 row-tiles + S-unit(rt=w) ----
        f32x4 acc[8], accS;
        {
            const f32x4 b1w = *(const f32x4*)(b1p + fw0 + q*4);
            const f32x4 b1S = *(const f32x4*)(b1p + 128 + q*4);
            #pragma unroll
            for (int rt = 0; rt < 8; ++rt) {
                int row = rt*16 + ln;                    // j = row>>5, b = row&31
                int sj = s0 + (row >> 5);                // clamp s ONLY, preserve b
                if (sj > 127) sj = 127;
                int rowg = sj*32 + (row & 31);
                half4 p = *(const half4*)(PW + (size_t)rowg*NP + fw0 + q*4);
                acc[rt] = b1w;
                #pragma unroll
                for (int i = 0; i < 4; ++i) acc[rt][i] += (float)p[i];
                if (rt == w) {
                    half4 pS = *(const half4*)(PW + (size_t)rowg*NP + 128 + q*4);
                    accS = b1S;
                    #pragma unroll
                    for (int i = 0; i < 4; ++i) accS[i] += (float)pS[i];
                }
            }
            #pragma unroll
            for (int kst = 0; kst < 4; ++kst) {
                half8 wA = *(const half8*)(W1t + (fw0+ln)*128 + kst*32 + q*8);
                half8 wS = *(const half8*)(W1t + (128+ln)*128 + kst*32 + q*8);
                int kb = kst*4 + q;
                #pragma unroll
                for (int rt = 0; rt < 8; ++rt) {
                    int row = rt*16 + ln;                // row & 15 == ln
                    half8 bf = *(const half8*)(cmx + row*128 + ((kb ^ ln)*8));
                    acc[rt] = MFMA(wA, bf, acc[rt]);
                    if (rt == w) accS = MFMA(wS, bf, accS);
                }
            }
        }
        __syncthreads();                             // [A2] all cmx reads done
        #pragma unroll
        for (int rt = 0; rt < 8; ++rt) {             // relu -> h1 over hB
            int row = rt*16 + ln;
            half4 hv;
            #pragma unroll
            for (int i = 0; i < 4; ++i) hv[i] = (_Float16)fmaxf(acc[rt][i], 0.f);
            *(half4*)(hB + row*HSTR2 + fw0 + q*4) = hv;
        }
        {
            int row = w*16 + ln;
            half4 hv;
            #pragma unroll
            for (int i = 0; i < 4; ++i) hv[i] = (_Float16)fmaxf(accS[i], 0.f);
            *(half4*)(hB + row*HSTR2 + 128 + q*4) = hv;
        }
        __syncthreads();                             // [B]

        // ---- L2': same balanced split, K=160 (zstrip covers cols 144..159) ----
        half4 h2[8], h2S;
        {
            const f32x4 b2w = *(const f32x4*)(b2p + fw0 + q*4);
            const f32x4 b2S = *(const f32x4*)(b2p + 128 + q*4);
            #pragma unroll
            for (int rt = 0; rt < 8; ++rt) acc[rt] = b2w;
            accS = b2S;
            #pragma unroll
            for (int kst = 0; kst < 5; ++kst) {
                half8 wA = *(const half8*)(W2t + (fw0+ln)*160 + kst*32 + q*8);
                half8 wS = *(const half8*)(W2t + (128+ln)*160 + kst*32 + q*8);
                #pragma unroll
                for (int rt = 0; rt < 8; ++rt) {
                    int row = rt*16 + ln;
                    half8 bf = (kst < 4)
                        ? *(const half8*)(hB + row*HSTR2 + kst*32 + q*8)
                        : ((q < 2) ? *(const half8*)(hB + row*HSTR2 + 128 + q*8)
                                   : *(const half8*)zstrip);
                    acc[rt] = MFMA(wA, bf, acc[rt]);
                    if (rt == w) accS = MFMA(wS, bf, accS);
                }
            }
            #pragma unroll
            for (int rt = 0; rt < 8; ++rt)
                #pragma unroll
                for (int i = 0; i < 4; ++i) h2[rt][i] = (_Float16)fmaxf(acc[rt][i], 0.f);
            #pragma unroll
            for (int i = 0; i < 4; ++i) h2S[i] = (_Float16)fmaxf(accS[i], 0.f);
        }
        __syncthreads();                             // [C] all h1 reads done
        #pragma unroll
        for (int rt = 0; rt < 8; ++rt) {
            int row = rt*16 + ln;
            *(half4*)(hB + row*HSTR2 + fw0 + q*4) = h2[rt];
        }
        *(half4*)(hB + (w*16 + ln)*HSTR2 + 128 + q*4) = h2S;
        __syncthreads();                             // [D]

        // ---- L3': z3^T = W3^T @ h2^T (4 o-tiles x 2 row-halves, balanced) ----
        {
            const f32x4 bz3 = *(const f32x4*)(b3 + og*16 + q*4);
            f32x4 z[4];
            #pragma unroll
            for (int rj = 0; rj < 4; ++rj) z[rj] = bz3;
            #pragma unroll
            for (int kst = 0; kst < 5; ++kst) {
                half8 wO = *(const half8*)(W3t + (og*16+ln)*160 + kst*32 + q*8);
                #pragma unroll
                for (int rj = 0; rj < 4; ++rj) {
                    int row = (rg3*4 + rj)*16 + ln;
                    half8 bf = (kst < 4)
                        ? *(const half8*)(hB + row*HSTR2 + kst*32 + q*8)
                        : ((q < 2) ? *(const half8*)(hB + row*HSTR2 + 128 + q*8)
                                   : *(const half8*)zstrip);
                    z[rj] = MFMA(wO, bf, z[rj]);
                }
            }
            // rows encode (j = rg3*2 + (rj>>1), b = (rj&1)*16 + ln); clamped
            // rows duplicate (s=127, same b) -> merge all unconditionally
            #pragma unroll
            for (int i = 0; i < 4; ++i) {
                rz0[i] = fmaxf(rz0[i], fmaxf(z[0][i], z[2][i]));
                rz1[i] = fmaxf(rz1[i], fmaxf(z[1][i], z[3][i]));
            }
        }
        __syncthreads();                             // [E] protect hB for next item
    }

    // ---- final flush ----
    {
        float* scr = (float*)hB;
        if (rg3 == 1) {
            *(f32x4*)(scr + (og*64 + lane)*8)     = rz0;
            *(f32x4*)(scr + (og*64 + lane)*8 + 4) = rz1;
        }
        __syncthreads();
        if (rg3 == 0) {
            f32x4 p0 = *(const f32x4*)(scr + (og*64 + lane)*8);
            f32x4 p1 = *(const f32x4*)(scr + (og*64 + lane)*8 + 4);
            #pragma unroll
            for (int i = 0; i < 4; ++i) {
                rz0[i] = fmaxf(rz0[i], p0[i]);
                rz1[i] = fmaxf(rz1[i], p1[i]);
            }
            int k = bid - bid_of(2*(cur_t >> 2)*(65 - (cur_t >> 2))
                                 + (cur_t - 4*(cur_t >> 2))*(32 - (cur_t >> 2)));
            _Float16* sp = slots + ((size_t)cur_t*KSLOT + k)*2048;
            int o = og*16 + q*4;
            half4 z0, z1;
            #pragma unroll
            for (int i = 0; i < 4; ++i) { z0[i] = (_Float16)rz0[i]; z1[i] = (_Float16)rz1[i]; }
            __builtin_nontemporal_store(z0, (half4*)(sp + ln*64 + o));
            __builtin_nontemporal_store(z1, (half4*)(sp + (16+ln)*64 + o));
        }
    }
}

extern "C" void kernel_launch(void* const* d_in, const int* in_sizes, int n_in,
                              void* d_out, int out_size, void* d_ws, size_t ws_size,
                              hipStream_t stream) {
    const float* P  = (const float*)d_in[0];
    const float* W1 = (const float*)d_in[1];
    const float* b1 = (const float*)d_in[2];
    const float* W2 = (const float*)d_in[3];
    const float* b2 = (const float*)d_in[4];
    const float* W3 = (const float*)d_in[5];
    const float* b3 = (const float*)d_in[6];

    tll_prep<<<240, 256, 0, stream>>>(P, W1, b1, W2, b2, W3, (char*)d_ws);

    hipFuncSetAttribute((const void*)tll_main,
                        hipFuncAttributeMaxDynamicSharedMemorySize, 38944);
    tll_main<<<NBLK, 512, 38944, stream>>>(b3, (char*)d_ws);

    tll_finalize<<<128, 512, 0, stream>>>((const char*)d_ws, (float*)d_out);
}